// Round 4
// baseline (118.465 us; speedup 1.0000x reference)
//
#include <hip/hip_runtime.h>
#include <hip/hip_bf16.h>

// CapsuleLayer on MI355X — barrier-free MFMA implicit-GEMM.
// b stays 0 (faithful torch bug) => one dense conv 64ci -> 128co, 5x5, pad 2,
// then v = squash_z1(p/(8*cnt)) and transpose to [N, t1, z1, H, W].
// Conv = 50-step K loop (25 shifts x 2 k-halves): C[256pix,128co] += A x B.
// A tile staged ONCE in LDS (padded rows, all frag addrs = base + scalar(kk));
// B streamed from L2 (400 KB, hot) with register double-buffer. No barriers
// inside the K loop.

#define CI 64
#define CO 128

typedef __attribute__((ext_vector_type(8))) short bf16x8;
typedef __attribute__((ext_vector_type(4))) float f32x4;

// ---- W fp32 [t0][co][z0][5][5] -> Wr2 bf16 [kk][co][ci]
__global__ __launch_bounds__(256) void k_reorder(const float* __restrict__ Wsrc,
                                                 ushort* __restrict__ Wr2) {
    int idx = blockIdx.x * 256 + threadIdx.x;   // (kk*128+co)*64+ci
    if (idx >= 25 * 128 * 64) return;
    int ci = idx & 63;
    int r  = idx >> 6;
    int co = r & 127;
    int kk = r >> 7;
    int t0 = ci >> 4, z0 = ci & 15;
    __hip_bfloat16 b = __float2bfloat16(Wsrc[((t0 * CO + co) * 16 + z0) * 25 + kk]);
    Wr2[idx] = *(ushort*)&b;
}

// ---- main: grid 256 = 4(n) x 8(hy) x 8(wx), 512 threads = 8 waves (2M x 4N)
// wave: wm = wid>>2 -> image rows [h0+wm*8, +8); wn = wid&3 -> co [wn*32, +32)
__global__ __launch_bounds__(512) void k_caps(const float* __restrict__ u,
                                              const ushort* __restrict__ Wr2,
                                              float* __restrict__ out) {
    // [p = rr*20+cc][ci], row stride 80 ushorts (160 B: 16B pad -> b128-aligned,
    // frag-read banks uniform 2/bank = free). 64000 B.
    __shared__ ushort As[400 * 80];

    int tid = threadIdx.x;
    int bid = blockIdx.x;
    int bx = bid & 7, by = (bid >> 3) & 7, n = bid >> 6;
    int h0 = by * 16, w0 = bx * 16;

    const float* ub = u + (size_t)n * (CI * 128 * 128);

    // ---- stage A: 20x20 pixels (halo 2, zero OOB) x 64 ci, fp32 -> bf16.
    // Lane = ci (2-way LDS bank aliasing = free); rr uniform per wave.
    // Chunks of 4 cols are provably fully-in or fully-out of [0,128).
#pragma unroll
    for (int j = 0; j < 3; ++j) {
        int P = tid + j * 512;
        if (P < 1280) {
            int rr = P >> 6, ci = P & 63;
            int hh = h0 + rr - 2;
            bool rok = (unsigned)hh < 128u;
            const float* src = ub + (((size_t)ci << 7) + hh) * 128 + (w0 - 4);
            float4 ch[6];
#pragma unroll
            for (int k = 0; k < 6; ++k) {
                int wc = w0 - 4 + k * 4;
                ch[k] = (rok && (unsigned)wc < 128u)
                            ? *(const float4*)(src + k * 4)
                            : make_float4(0.f, 0.f, 0.f, 0.f);
            }
#pragma unroll
            for (int k = 0; k < 6; ++k) {
                float vals[4] = {ch[k].x, ch[k].y, ch[k].z, ch[k].w};
#pragma unroll
                for (int e = 0; e < 4; ++e) {
                    int cc = k * 4 + e - 2;
                    if ((unsigned)cc < 20u) {
                        __hip_bfloat16 bv = __float2bfloat16(vals[e]);
                        As[(rr * 20 + cc) * 80 + ci] = *(ushort*)&bv;
                    }
                }
            }
        }
    }
    __syncthreads();   // the ONLY barrier

    int lane = tid & 63, wid = tid >> 6;
    int wm = wid >> 2;           // 0..1
    int wn = wid & 3;            // 0..3
    int q = lane >> 4, m16 = lane & 15;

    f32x4 acc[8][2] = {};

    // A frag (mi, kk, ks): ushort idx = aBase + (kh*20+kw)*80 + ks*32 + mi*1600
    int aBase = (wm * 160 + m16) * 80 + q * 8;

    // B frag: Wr2[kk][co = wn*32 + ni*16 + m16][ci = ks*32 + q*8 ..+8]
    const ushort* bp = Wr2 + (wn * 32 + m16) * 64 + q * 8;
    bf16x8 bnxt0 = *(const bf16x8*)bp;
    bf16x8 bnxt1 = *(const bf16x8*)(bp + 1024);   // ni=1: +16 co

    int soff = 0, kw = 0;
    for (int step = 0; step < 50; ++step) {
        int ks = step & 1;
        bf16x8 b0 = bnxt0, b1 = bnxt1;
        bp += ks ? (8192 - 32) : 32;              // next ks / next kk
        if (step < 49) {
            bnxt0 = *(const bf16x8*)bp;
            bnxt1 = *(const bf16x8*)(bp + 1024);
        }
        int au = aBase + soff + ks * 32;
        bf16x8 a[8];
#pragma unroll
        for (int mi = 0; mi < 8; ++mi)
            a[mi] = *(const bf16x8*)(As + au + mi * 1600);
#pragma unroll
        for (int mi = 0; mi < 8; ++mi) {
            acc[mi][0] = __builtin_amdgcn_mfma_f32_16x16x32_bf16(a[mi], b0, acc[mi][0], 0, 0, 0);
            acc[mi][1] = __builtin_amdgcn_mfma_f32_16x16x32_bf16(a[mi], b1, acc[mi][1], 0, 0, 0);
        }
        if (ks) {                                  // advance (kh,kw) scalar offset
            if (kw < 4) { kw++; soff += 80; }
            else        { kw = 0; soff += 1280; }  // (20-4)*80
        }
    }

    // ---- epilogue: scale 1/(8*cnt), squash over z1 (= m16 lanes), store
    // D layout: row(m = image col) = q*4+reg, col(n = co) = m16
#pragma unroll
    for (int mi = 0; mi < 8; ++mi) {
        int h = h0 + wm * 8 + mi;
        int hlo = h - 2; if (hlo < 0) hlo = 0;
        int hhi = h + 2; if (hhi > 127) hhi = 127;
        float cnth = (float)(hhi - hlo + 1);
#pragma unroll
        for (int ni = 0; ni < 2; ++ni) {
            f32x4 cv = acc[mi][ni];
            float ov[4];
#pragma unroll
            for (int reg = 0; reg < 4; ++reg) {
                int w = w0 + q * 4 + reg;
                int wlo = w - 2; if (wlo < 0) wlo = 0;
                int whi = w + 2; if (whi > 127) whi = 127;
                float s = 1.f / (8.f * cnth * (float)(whi - wlo + 1));
                float pv = cv[reg] * s;
                float n2 = pv * pv;
                n2 += __shfl_xor(n2, 1);
                n2 += __shfl_xor(n2, 2);
                n2 += __shfl_xor(n2, 4);
                n2 += __shfl_xor(n2, 8);
                float fac = n2 / ((1.f + n2) * sqrtf(n2 + 1e-9f));
                ov[reg] = pv * fac;
            }
            int co = wn * 32 + ni * 16 + m16;
            *(float4*)(out + (((size_t)(n * CO + co)) << 14) + h * 128 + w0 + q * 4) =
                make_float4(ov[0], ov[1], ov[2], ov[3]);
        }
    }
}

extern "C" void kernel_launch(void* const* d_in, const int* in_sizes, int n_in,
                              void* d_out, int out_size, void* d_ws, size_t ws_size,
                              hipStream_t stream) {
    const float* u    = (const float*)d_in[0];
    const float* Wsrc = (const float*)d_in[1];
    float* out = (float*)d_out;
    ushort* Wr2 = (ushort*)d_ws;   // 409600 B

    k_reorder<<<800, 256, 0, stream>>>(Wsrc, Wr2);
    k_caps<<<256, 512, 0, stream>>>(u, Wr2, out);
}